// Round 2
// baseline (3120.578 us; speedup 1.0000x reference)
//
#include <hip/hip_runtime.h>

#define H 64
#define T_STEPS 2048

typedef _Float16 h2_t __attribute__((ext_vector_type(2)));
typedef _Float16 h8_t __attribute__((ext_vector_type(8)));

__device__ __forceinline__ float tanh_f(float x) {
    return 2.0f / (1.0f + __expf(-2.0f * x)) - 1.0f;
}

#if __has_builtin(__builtin_amdgcn_fdot2)
__device__ __forceinline__ float dot2(h2_t a, h2_t b, float c) {
    return __builtin_amdgcn_fdot2(a, b, c, false);
}
#else
__device__ __forceinline__ float dot2(h2_t a, h2_t b, float c) {
    float r;
    asm volatile("v_dot2_f32_f16 %0, %1, %2, %3"
                 : "=v"(r) : "v"(a), "v"(b), "v"(c));
    return r;
}
#endif

#define SUB2(v, i) __builtin_shufflevector((v), (v), (i), (i) + 1)

__device__ __forceinline__ float d8(h8_t wv, h8_t hv, float acc) {
    acc = dot2(SUB2(wv, 0), SUB2(hv, 0), acc);
    acc = dot2(SUB2(wv, 2), SUB2(hv, 2), acc);
    acc = dot2(SUB2(wv, 4), SUB2(hv, 4), acc);
    acc = dot2(SUB2(wv, 6), SUB2(hv, 6), acc);
    return acc;
}

// 64-dot from PRELOADED fragments: 4 independent 8-dot2 chains.
#define DOTROW8V(Wa, Wb, Wc, Wd, We, Wf, Wg, Wh, f0, f1, f2, f3, f4, f5, f6, f7) \
    ((d8(Wb, f1, d8(Wa, f0, 0.f)) + d8(Wd, f3, d8(Wc, f2, 0.f)))                 \
   + (d8(Wf, f5, d8(We, f4, 0.f)) + d8(Wh, f7, d8(Wg, f6, 0.f))))

// load 16 fp32 weights -> two h8_t (load-time only)
__device__ __forceinline__ void cvt16(const float* __restrict__ src,
                                      h8_t& a, h8_t& b) {
    const float4* p = (const float4*)src;
    float4 v0 = p[0], v1 = p[1], v2 = p[2], v3 = p[3];
    a[0] = (_Float16)v0.x; a[1] = (_Float16)v0.y;
    a[2] = (_Float16)v0.z; a[3] = (_Float16)v0.w;
    a[4] = (_Float16)v1.x; a[5] = (_Float16)v1.y;
    a[6] = (_Float16)v1.z; a[7] = (_Float16)v1.w;
    b[0] = (_Float16)v2.x; b[1] = (_Float16)v2.y;
    b[2] = (_Float16)v2.z; b[3] = (_Float16)v2.w;
    b[4] = (_Float16)v3.x; b[5] = (_Float16)v3.y;
    b[6] = (_Float16)v3.z; b[7] = (_Float16)v3.w;
}

// activation + quad gate gather (gate = l&3 -> xor 1/2/3 are DPP
// quad_perm, full rate) + cell update. pre: full row pre-activation.
__device__ __forceinline__ float cell_update(float pre, bool isg,
                                             bool b0, bool b1, float& cst) {
    float zz  = isg ? (-2.0f * pre) : (-pre);
    float ex  = __expf(zz);
    float rr  = 1.0f / (1.0f + ex);
    float act = isg ? (2.0f * rr - 1.0f) : rr;
    float a1 = __shfl_xor(act, 1);     // gate^1 (quad_perm)
    float a2 = __shfl_xor(act, 2);     // gate^2 (quad_perm)
    float a3 = __shfl_xor(act, 3);     // gate^3 (quad_perm)
    float q0 = b0 ? a1 : act, q1 = b0 ? act : a1;
    float q2 = b0 ? a3 : a2,  q3 = b0 ? a2 : a3;
    float gi = b1 ? q2 : q0;           // i
    float gf = b1 ? q3 : q1;           // f
    float gg = b1 ? q0 : q2;           // g
    float go = b1 ? q1 : q3;           // o
    cst = gf * cst + gi * gg;
    return go * tanh_f(cst);
}

// R15: EXPLICIT AGPR WEIGHT PARKING + CONFLICT-FREE h LAYOUT + QUAD GATES.
// R14 post-mortem: VGPR_Count=64 (allocator's hard arch cap, 15 rounds
// running) with 52 "+v"-pinned weights -> ~12 arch regs for a 32-reg h
// working set -> ds_read/dot serialization (~1000 exposed LDS-latency
// cyc/step); plus 2.7e8 bank conflicts (h buffers 256B apart = same bank
// quad for hf pairs).
// R15: (1) weights pinned "+a" (AGPR home; v_accvgpr_read per use ~1
// VALU, arch file freed for fully-pipelined h prefetch);
// (2) h buffers padded to 72 halves (144B) -> hf-pair addresses differ
// by 16 mod 128 -> disjoint bank quads;
// (3) lane remap: gate=l&3 (quad -> DPP gathers), hf=(l>>2)&1 (xor 4
// combine), cell=(w&7)*8+(l>>3).
// Same layer pipeline: waves 0-7 = L0+L1, waves 8-15 = L2; t = p - layer.
__global__ __launch_bounds__(1024, 4)
void lstm3_r15(const float* __restrict__ x,
               const float* __restrict__ Wih0, const float* __restrict__ Whh0,
               const float* __restrict__ bih0, const float* __restrict__ bhh0,
               const float* __restrict__ Wih1, const float* __restrict__ Whh1,
               const float* __restrict__ bih1, const float* __restrict__ bhh1,
               const float* __restrict__ Wih2, const float* __restrict__ Whh2,
               const float* __restrict__ bih2, const float* __restrict__ bhh2,
               const float* __restrict__ Wout, const float* __restrict__ bout,
               float* __restrict__ out)
{
    __shared__ __align__(16) float xs[T_STEPS * 2];     // 16 KB input seq
    // h storage: [slot][layer*72 + cell]; 72-half (144B) stride =>
    // layer bases at 0/16/32 mod 128 -> no inter-buffer bank aliasing.
    __shared__ __align__(16) _Float16 hst[2][224];
    __shared__ __align__(16) float h2f[H];

    const int tid  = threadIdx.x;
    const int b    = blockIdx.x;
    const int w    = tid >> 6;               // wave 0..15
    const int l    = tid & 63;
    const int gate = l & 3;                  // 0:i 1:f 2:g 3:o (quad)
    const int hf   = (l >> 2) & 1;           // matrix half
    const int cell = (w & 7) * 8 + (l >> 3);
    const int row  = gate * H + cell;        // gate row 0..255
    const bool isL01 = (w < 8);              // wave-uniform
    const bool isg = (gate == 2);
    const bool b0g = (gate & 1) != 0, b1g = (gate & 2) != 0;

    // ---- stage x[b,:,:]: exactly one float4 per thread ----
    ((float4*)xs)[tid] = ((const float4*)(x + (size_t)b * T_STEPS * 2))[tid];

    // ---- weights: this lane's row(s), parked in AGPRs ----
    h8_t W0, W1, W2, W3, W4, W5, W6, W7;   // L1/L2 matrix row (64 w)
    h8_t X0, X1, X2, X3;                   // L0 half-row (32 w), waves 0-7
    float wx0 = 0.f, wx1 = 0.f, biasL = 0.f, bias0 = 0.f;
    if (isL01) {
        const float* m = (hf ? Whh1 : Wih1) + row * H;
        cvt16(m,      W0, W1); cvt16(m + 16, W2, W3);
        cvt16(m + 32, W4, W5); cvt16(m + 48, W6, W7);
        const float* m0 = Whh0 + row * H + hf * 32;
        cvt16(m0, X0, X1); cvt16(m0 + 16, X2, X3);
        if (!hf) { wx0 = Wih0[row * 2]; wx1 = Wih0[row * 2 + 1]; }
        biasL = bih1[row] + bhh1[row];
        bias0 = bih0[row] + bhh0[row];
    } else {
        const float* m = (hf ? Whh2 : Wih2) + row * H;
        cvt16(m,      W0, W1); cvt16(m + 16, W2, W3);
        cvt16(m + 32, W4, W5); cvt16(m + 48, W6, W7);
        biasL = bih2[row] + bhh2[row];
#pragma unroll
        for (int i = 0; i < 8; ++i) {
            X0[i] = (_Float16)0.f; X1[i] = (_Float16)0.f;
            X2[i] = (_Float16)0.f; X3[i] = (_Float16)0.f;
        }
    }
    // park in AGPRs now (setup-time accvgpr_write)
    asm volatile("" : "+a"(W0), "+a"(W1), "+a"(W2), "+a"(W3));
    asm volatile("" : "+a"(W4), "+a"(W5), "+a"(W6), "+a"(W7));
    asm volatile("" : "+a"(X0), "+a"(X1), "+a"(X2), "+a"(X3));
    asm volatile("" : "+v"(wx0), "+v"(wx1), "+v"(biasL), "+v"(bias0));

    {   // zero h state (both slots, incl. padding)
        if (tid < 448) ((_Float16*)hst)[tid] = (_Float16)0.f;
    }
    float cstL = 0.f, cst0 = 0.f;
    __syncthreads();

#pragma unroll 1
    for (int p = 0; p < T_STEPS + 2; ++p) {
        // re-pin each iteration: weights' home stays AGPR, arch file
        // stays free for the h-fragment prefetch below.
        asm volatile("" : "+a"(W0), "+a"(W1), "+a"(W2), "+a"(W3));
        asm volatile("" : "+a"(W4), "+a"(W5), "+a"(W6), "+a"(W7));
        asm volatile("" : "+a"(X0), "+a"(X1), "+a"(X2), "+a"(X3));
        const int s  = (p + 1) & 1;    // read slot
        const int wr = p & 1;          // write slot
        const _Float16* hb = hst[s];
        if (isL01) {
            if (p < T_STEPS) {         // ---- L0, t = p ----
                const h8_t* hp = (const h8_t*)(hb + hf * 32);
                h8_t e0 = hp[0], e1 = hp[1], e2 = hp[2], e3 = hp[3];
                float2 xt = *(const float2*)&xs[2 * p];
                float part = d8(X1, e1, d8(X0, e0, 0.f))
                           + d8(X3, e3, d8(X2, e2, 0.f))
                           + wx0 * xt.x + wx1 * xt.y;   // 0 on hf=1
                part += __shfl_xor(part, 4);            // combine halves
                float hh = cell_update(part + bias0, isg, b0g, b1g, cst0);
                if ((l & 7) == 0)                       // gate==0 && hf==0
                    hst[wr][cell] = (_Float16)hh;
            }
            if (p >= 1 && p <= T_STEPS) {   // ---- L1, t = p-1 ----
                const h8_t* hp = (const h8_t*)(hb + (hf ? 72 : 0));
                h8_t f0 = hp[0], f1 = hp[1], f2 = hp[2], f3 = hp[3];
                h8_t f4 = hp[4], f5 = hp[5], f6 = hp[6], f7 = hp[7];
                float part = DOTROW8V(W0, W1, W2, W3, W4, W5, W6, W7,
                                      f0, f1, f2, f3, f4, f5, f6, f7);
                part += __shfl_xor(part, 4);
                float hh = cell_update(part + biasL, isg, b0g, b1g, cstL);
                if ((l & 7) == 0)
                    hst[wr][72 + cell] = (_Float16)hh;
            }
        } else {
            if (p >= 2) {                   // ---- L2, t = p-2 ----
                const h8_t* hp = (const h8_t*)(hb + 72 + (hf ? 72 : 0));
                h8_t f0 = hp[0], f1 = hp[1], f2 = hp[2], f3 = hp[3];
                h8_t f4 = hp[4], f5 = hp[5], f6 = hp[6], f7 = hp[7];
                float part = DOTROW8V(W0, W1, W2, W3, W4, W5, W6, W7,
                                      f0, f1, f2, f3, f4, f5, f6, f7);
                part += __shfl_xor(part, 4);
                float hh = cell_update(part + biasL, isg, b0g, b1g, cstL);
                if ((l & 7) == 0) {
                    hst[wr][144 + cell] = (_Float16)hh;
                    if (p == T_STEPS + 1) h2f[cell] = hh;  // final h
                }
            }
        }
        __syncthreads();
    }

    // ---- fused projection: out[b,:] = h2_last @ Wout^T + bout ----
    if (tid < 11) {
        float acc = bout[tid];
#pragma unroll
        for (int jj = 0; jj < H; ++jj)
            acc += Wout[tid * H + jj] * h2f[jj];
        out[b * 11 + tid] = acc;
    }
}

extern "C" void kernel_launch(void* const* d_in, const int* in_sizes, int n_in,
                              void* d_out, int out_size, void* d_ws, size_t ws_size,
                              hipStream_t stream) {
    const float* x    = (const float*)d_in[0];
    const float* Wih0 = (const float*)d_in[1];
    const float* Whh0 = (const float*)d_in[2];
    const float* bih0 = (const float*)d_in[3];
    const float* bhh0 = (const float*)d_in[4];
    const float* Wih1 = (const float*)d_in[5];
    const float* Whh1 = (const float*)d_in[6];
    const float* bih1 = (const float*)d_in[7];
    const float* bhh1 = (const float*)d_in[8];
    const float* Wih2 = (const float*)d_in[9];
    const float* Whh2 = (const float*)d_in[10];
    const float* bih2 = (const float*)d_in[11];
    const float* bhh2 = (const float*)d_in[12];
    const float* Wout = (const float*)d_in[13];
    const float* bout = (const float*)d_in[14];
    float* out = (float*)d_out;

    lstm3_r15<<<256, 1024, 0, stream>>>(x,
        Wih0, Whh0, bih0, bhh0,
        Wih1, Whh1, bih1, bhh1,
        Wih2, Whh2, bih2, bhh2,
        Wout, bout, out);
}

// Round 3
// 1854.985 us; speedup vs baseline: 1.6823x; 1.6823x over previous
//
#include <hip/hip_runtime.h>

#define H 64
#define T_STEPS 2048

typedef _Float16 f16x8 __attribute__((ext_vector_type(8)));
typedef float    f32x4 __attribute__((ext_vector_type(4)));

__device__ __forceinline__ float sig_f(float x) {
    return 1.0f / (1.0f + __expf(-x));
}
__device__ __forceinline__ float tanh_f(float x) {
    return 2.0f / (1.0f + __expf(-2.0f * x)) - 1.0f;
}

// load 8 consecutive f32 -> f16x8 (setup only)
__device__ __forceinline__ f16x8 ldcvt8(const float* __restrict__ p) {
    float4 a = ((const float4*)p)[0];
    float4 c = ((const float4*)p)[1];
    f16x8 r;
    r[0]=(_Float16)a.x; r[1]=(_Float16)a.y; r[2]=(_Float16)a.z; r[3]=(_Float16)a.w;
    r[4]=(_Float16)c.x; r[5]=(_Float16)c.y; r[6]=(_Float16)c.z; r[7]=(_Float16)c.w;
    return r;
}

#define MFMA(a, b, c) __builtin_amdgcn_mfma_f32_16x16x32_f16((a), (b), (c), 0, 0, 0)

// R16: MFMA MATVEC — weights live in AGPRs, consumed in place.
// R13-R15 lesson: allocator grants ~64 arch VGPRs; v_dot2 can't read
// AGPRs -> every dot2 design pays per-use copies or LDS latency. MFMA
// reads A/B from AGPRs natively (ISA §10) -> per-step copy cost = 0.
//
// Per phase p (layer pipeline L0:t=p, L1:p-1, L2:p-2, all reading
// phase-(p-1) state): G = Wperm @ S, S = [h0;h1;h2] (f16, LDS, K-chunks
// of 32). Wave w owns permuted-row tile 16w..16w+15 of each layer
// (row' = cell*4+gate -> D lane (col 0, reg r) = gate r of cell 4w+kg:
// all 4 gates of a cell in ONE lane). MFMAs: L0 2 + L1 4 + L2 4 = 10/wave.
// B-frag: lanes l&15==0 read S chunk (4 lanes, b128); others read a
// zero pad (broadcast) -> B cols 1-15 = 0.
// Gates -> gbuf (LDS) -> barrier -> act waves 0-2 (layer w, lane=cell):
// bias + x-term (f32, wave 0) + sigmoid/tanh + c,h update -> h (f16) to
// S write slot. 2 barriers/step.
__global__ __launch_bounds__(1024, 4)
void lstm3_r16(const float* __restrict__ x,
               const float* __restrict__ Wih0, const float* __restrict__ Whh0,
               const float* __restrict__ bih0, const float* __restrict__ bhh0,
               const float* __restrict__ Wih1, const float* __restrict__ Whh1,
               const float* __restrict__ bih1, const float* __restrict__ bhh1,
               const float* __restrict__ Wih2, const float* __restrict__ Whh2,
               const float* __restrict__ bih2, const float* __restrict__ bhh2,
               const float* __restrict__ Wout, const float* __restrict__ bout,
               float* __restrict__ out)
{
    __shared__ __align__(16) float xs[T_STEPS * 2];   // 16 KB input seq (f32)
    // S: 2 slots x 384 halves (768 B). Rows 0-63 h0, 64-127 h1,
    // 128-191 h2; rows 192-383 permanent zeros (inactive-lane B reads).
    __shared__ __align__(16) _Float16 S[2][384];
    __shared__ __align__(16) float gbuf[3 * H * 4];   // pre-acts [layer][cell][gate]
    __shared__ __align__(16) float h2f[H];

    const int tid = threadIdx.x;
    const int b   = blockIdx.x;
    const int w   = tid >> 6;          // wave 0..15 = M-tile index
    const int l   = tid & 63;
    const int lj  = l & 15;            // A row-in-tile / B col
    const int kg  = l >> 4;            // k-group 0..3

    // ---- stage x[b,:,:]: one float4 per thread ----
    ((float4*)xs)[tid] = ((const float4*)(x + (size_t)b * T_STEPS * 2))[tid];

    // ---- A-fragments: permuted row' = 16w + lj <-> cell=4w+(lj>>2), gate=lj&3
    const int cellA = 4 * w + (lj >> 2);
    const int gateA = lj & 3;
    const int wrow  = gateA * H + cellA;   // row of the 256-row gate matrix
    const int kc    = kg * 8;              // k offset within a 64-col block

    f16x8 A00 = ldcvt8(Whh0 + wrow * H + kc);        // L0, S chunk 0 (h0)
    f16x8 A01 = ldcvt8(Whh0 + wrow * H + 32 + kc);   // L0, chunk 1
    f16x8 A10 = ldcvt8(Wih1 + wrow * H + kc);        // L1, chunk 0 (h0)
    f16x8 A11 = ldcvt8(Wih1 + wrow * H + 32 + kc);   // L1, chunk 1
    f16x8 A12 = ldcvt8(Whh1 + wrow * H + kc);        // L1, chunk 2 (h1)
    f16x8 A13 = ldcvt8(Whh1 + wrow * H + 32 + kc);   // L1, chunk 3
    f16x8 A20 = ldcvt8(Wih2 + wrow * H + kc);        // L2, chunk 2 (h1)
    f16x8 A21 = ldcvt8(Wih2 + wrow * H + 32 + kc);   // L2, chunk 3
    f16x8 A22 = ldcvt8(Whh2 + wrow * H + kc);        // L2, chunk 4 (h2)
    f16x8 A23 = ldcvt8(Whh2 + wrow * H + 32 + kc);   // L2, chunk 5
    // park in AGPRs once; MFMA consumes them there (no per-step copies)
    asm volatile("" : "+a"(A00), "+a"(A01), "+a"(A10), "+a"(A11));
    asm volatile("" : "+a"(A12), "+a"(A13), "+a"(A20), "+a"(A21));
    asm volatile("" : "+a"(A22), "+a"(A23));

    // ---- act-wave constants (waves 0-2 only; lane = cell) ----
    float biasv[4], wxv[8];
    float cst = 0.f;
    if (w < 3) {
        const float* bi = (w == 0) ? bih0 : (w == 1) ? bih1 : bih2;
        const float* bh = (w == 0) ? bhh0 : (w == 1) ? bhh1 : bhh2;
#pragma unroll
        for (int g = 0; g < 4; ++g) biasv[g] = bi[g * H + l] + bh[g * H + l];
        if (w == 0) {
#pragma unroll
            for (int g = 0; g < 4; ++g) {
                wxv[2 * g]     = Wih0[(g * H + l) * 2];
                wxv[2 * g + 1] = Wih0[(g * H + l) * 2 + 1];
            }
        }
    }

    // ---- zero S (both slots incl. zero pad) ----
    if (tid < 384) ((float*)S)[tid] = 0.f;
    __syncthreads();

    // B-frag byte offset within a slot: active lanes read their k-group,
    // inactive lanes read the zero pad (broadcast).
    const char* Sb  = (const char*)S;
    const int  bofs = (lj == 0) ? (kg * 16) : 384;

    const f32x4 z = {0.f, 0.f, 0.f, 0.f};

#pragma unroll 1
    for (int p = 0; p < T_STEPS + 2; ++p) {
        const int so = ((p + 1) & 1) * 768;        // read-slot byte offset
        const char* Bp = Sb + (bofs + so);
        f16x8 b0 = *(const f16x8*)(Bp + 0);        // S rows   0- 31 (h0 lo)
        f16x8 b1 = *(const f16x8*)(Bp + 64);       // S rows  32- 63 (h0 hi)
        f16x8 b2 = *(const f16x8*)(Bp + 128);      // S rows  64- 95 (h1 lo)
        f16x8 b3 = *(const f16x8*)(Bp + 192);      // S rows  96-127 (h1 hi)
        f16x8 b4 = *(const f16x8*)(Bp + 256);      // S rows 128-159 (h2 lo)
        f16x8 b5 = *(const f16x8*)(Bp + 320);      // S rows 160-191 (h2 hi)

        const bool on0 = (p < T_STEPS);
        const bool on1 = (p >= 1) && (p <= T_STEPS);
        const bool on2 = (p >= 2);

        f32x4 g0, g1, g2;
        if (on0) { g0 = MFMA(A00, b0, z);  g0 = MFMA(A01, b1, g0); }
        if (on1) { g1 = MFMA(A10, b0, z);  g1 = MFMA(A11, b1, g1);
                   g1 = MFMA(A12, b2, g1); g1 = MFMA(A13, b3, g1); }
        if (on2) { g2 = MFMA(A20, b2, z);  g2 = MFMA(A21, b3, g2);
                   g2 = MFMA(A22, b4, g2); g2 = MFMA(A23, b5, g2); }

        if (lj == 0) {                     // col 0 = the real matvec result
            const int ci = 4 * w + kg;     // cell; reg r = gate r
            if (on0) *(f32x4*)&gbuf[(0 * H + ci) * 4] = g0;
            if (on1) *(f32x4*)&gbuf[(1 * H + ci) * 4] = g1;
            if (on2) *(f32x4*)&gbuf[(2 * H + ci) * 4] = g2;
        }
        __syncthreads();

        if (w < 3) {                       // act wave w = layer w, lane = cell
            const bool on = (w == 0) ? on0 : (w == 1) ? on1 : on2;
            if (on) {
                float4 g = *(const float4*)&gbuf[(w * H + l) * 4];
                float pi = g.x + biasv[0], pf = g.y + biasv[1];
                float pg = g.z + biasv[2], po = g.w + biasv[3];
                if (w == 0) {              // x-term in f32 (not via MFMA)
                    float2 xt = *(const float2*)&xs[2 * p];
                    pi += wxv[0] * xt.x + wxv[1] * xt.y;
                    pf += wxv[2] * xt.x + wxv[3] * xt.y;
                    pg += wxv[4] * xt.x + wxv[5] * xt.y;
                    po += wxv[6] * xt.x + wxv[7] * xt.y;
                }
                float i_ = sig_f(pi), f_ = sig_f(pf);
                float g_ = tanh_f(pg), o_ = sig_f(po);
                cst = f_ * cst + i_ * g_;
                float hh = o_ * tanh_f(cst);
                S[p & 1][w * H + l] = (_Float16)hh;
                if (w == 2 && p == T_STEPS + 1) h2f[l] = hh;   // final h2
            }
        }
        __syncthreads();
    }

    // ---- fused projection: out[b,:] = h2_last @ Wout^T + bout ----
    if (tid < 11) {
        float acc = bout[tid];
#pragma unroll
        for (int jj = 0; jj < H; ++jj)
            acc += Wout[tid * H + jj] * h2f[jj];
        out[b * 11 + tid] = acc;
    }
}

extern "C" void kernel_launch(void* const* d_in, const int* in_sizes, int n_in,
                              void* d_out, int out_size, void* d_ws, size_t ws_size,
                              hipStream_t stream) {
    const float* x    = (const float*)d_in[0];
    const float* Wih0 = (const float*)d_in[1];
    const float* Whh0 = (const float*)d_in[2];
    const float* bih0 = (const float*)d_in[3];
    const float* bhh0 = (const float*)d_in[4];
    const float* Wih1 = (const float*)d_in[5];
    const float* Whh1 = (const float*)d_in[6];
    const float* bih1 = (const float*)d_in[7];
    const float* bhh1 = (const float*)d_in[8];
    const float* Wih2 = (const float*)d_in[9];
    const float* Whh2 = (const float*)d_in[10];
    const float* bih2 = (const float*)d_in[11];
    const float* bhh2 = (const float*)d_in[12];
    const float* Wout = (const float*)d_in[13];
    const float* bout = (const float*)d_in[14];
    float* out = (float*)d_out;

    lstm3_r16<<<256, 1024, 0, stream>>>(x,
        Wih0, Whh0, bih0, bhh0,
        Wih1, Whh1, bih1, bhh1,
        Wih2, Whh2, bih2, bhh2,
        Wout, bout, out);
}